// Round 5
// baseline (260.807 us; speedup 1.0000x reference)
//
#include <hip/hip_runtime.h>
#include <math.h>

#define B_   4
#define N_   4096
#define C_   512
#define C8_  64
#define C2_  256
#define LOG2E 1.44269504f

typedef __attribute__((ext_vector_type(8))) short bf16x8;
typedef __attribute__((ext_vector_type(4))) short bf16x4;
typedef __attribute__((ext_vector_type(4))) float floatx4;
typedef __attribute__((ext_vector_type(16))) float floatx16;

__device__ __forceinline__ short f2bf(float x) {
    unsigned u = __float_as_uint(x);
    u += 0x7fff + ((u >> 16) & 1);          // round-to-nearest-even
    return (short)(u >> 16);
}
// pack2: (bf(a) | bf(b)<<16) with round-half-up via v_perm_b32 (3 VALU ops)
__device__ __forceinline__ unsigned pack2bf_fast(float a, float b) {
    unsigned ua = __float_as_uint(a) + 0x8000u;
    unsigned ub = __float_as_uint(b) + 0x8000u;
    return __builtin_amdgcn_perm(ub, ua, 0x07060302u);
}
__device__ __forceinline__ float bf2f(short s) {
    return __uint_as_float(((unsigned)(unsigned short)s) << 16);
}

union U8 { bf16x8 v; unsigned u[4]; };

// ---------------------------------------------------------------------------
// Kernel 0: weight prep.  WcatT[384][512] = [Wf|Wg|Wh]^T,  WoT[512][256] = Wo^T
// ---------------------------------------------------------------------------
__global__ __launch_bounds__(256) void convert_w(
    const float* __restrict__ Wf, const float* __restrict__ Wg,
    const float* __restrict__ Wh, const float* __restrict__ Wo,
    short* __restrict__ WcatT, short* __restrict__ WoT)
{
    int tid = blockIdx.x * 256 + threadIdx.x;
    if (tid < 384 * 512) {
        int n = tid >> 9, k = tid & 511;
        float v = (n < 64)  ? Wf[k * 64 + n]
                : (n < 128) ? Wg[k * 64 + (n - 64)]
                            : Wh[k * 256 + (n - 128)];
        WcatT[tid] = f2bf(v);
    } else {
        int t2 = tid - 384 * 512;      // < 512*256
        int n = t2 >> 8, k = t2 & 255;
        WoT[t2] = f2bf(Wo[k * 512 + n]);
    }
}

// ---------------------------------------------------------------------------
// Kernel 1: qkv MFMA GEMM.  g is pre-scaled by log2(e) (softmax uses exp2).
// ---------------------------------------------------------------------------
__global__ __launch_bounds__(256, 2) void qkv_mfma(
    const float* __restrict__ x, const short* __restrict__ WcatT,
    const float* __restrict__ bfv, const float* __restrict__ bgv,
    const float* __restrict__ bhv,
    short* __restrict__ fbf, short* __restrict__ gbf, short* __restrict__ hT)
{
    const int ny = blockIdx.x;           // 0..2
    const int m0 = blockIdx.y * 128;
    const int n0 = ny * 128;
    const int t  = threadIdx.x;
    const int w  = t >> 6, lane = t & 63;
    const int l15 = lane & 15, quad = lane >> 4;
    const int wm = w & 1, wn = w >> 1;

    __shared__ short As[128 * 40];
    __shared__ short Bs[128 * 40];

    floatx4 acc[4][4];
    #pragma unroll
    for (int i = 0; i < 4; i++)
        #pragma unroll
        for (int j = 0; j < 4; j++) acc[i][j] = (floatx4){0.f,0.f,0.f,0.f};

    for (int k0 = 0; k0 < C_; k0 += 32) {
        #pragma unroll
        for (int i = 0; i < 4; i++) {
            int c = t + i * 256;
            int row = c >> 3, ko = (c & 7) * 4;
            float4 v = *(const float4*)&x[(size_t)(m0 + row) * C_ + k0 + ko];
            bf16x4 pk = { f2bf(v.x), f2bf(v.y), f2bf(v.z), f2bf(v.w) };
            *(bf16x4*)&As[row * 40 + ko] = pk;
        }
        #pragma unroll
        for (int i = 0; i < 2; i++) {
            int c = t + i * 256;
            int nr = c >> 2, ko = (c & 3) * 8;
            *(bf16x8*)&Bs[nr * 40 + ko] =
                *(const bf16x8*)&WcatT[(size_t)(n0 + nr) * 512 + k0 + ko];
        }
        __syncthreads();

        bf16x8 af[4], bfr[4];
        #pragma unroll
        for (int mt = 0; mt < 4; mt++)
            af[mt] = *(const bf16x8*)&As[(wm * 64 + mt * 16 + l15) * 40 + quad * 8];
        #pragma unroll
        for (int nt = 0; nt < 4; nt++)
            bfr[nt] = *(const bf16x8*)&Bs[(wn * 64 + nt * 16 + l15) * 40 + quad * 8];
        #pragma unroll
        for (int mt = 0; mt < 4; mt++)
            #pragma unroll
            for (int nt = 0; nt < 4; nt++)
                acc[mt][nt] = __builtin_amdgcn_mfma_f32_16x16x32_bf16(af[mt], bfr[nt], acc[mt][nt], 0, 0, 0);
        __syncthreads();
    }

    if (ny == 0) {
        #pragma unroll
        for (int mt = 0; mt < 4; mt++) {
            #pragma unroll
            for (int nt = 0; nt < 4; nt++) {
                int cn = wn * 64 + nt * 16 + l15;
                #pragma unroll
                for (int rg = 0; rg < 4; rg++) {
                    int row = m0 + wm * 64 + mt * 16 + quad * 4 + rg;
                    float v = acc[mt][nt][rg];
                    if (cn < 64) fbf[(size_t)row * 64 + cn]        = f2bf(v + bfv[cn]);
                    else         gbf[(size_t)row * 64 + (cn - 64)] = f2bf((v + bgv[cn - 64]) * LOG2E);
                }
            }
        }
    } else {
        #pragma unroll
        for (int mt = 0; mt < 4; mt++) {
            #pragma unroll
            for (int nt = 0; nt < 4; nt++) {
                int hch = (ny - 1) * 128 + wn * 64 + nt * 16 + l15;
                int row = m0 + wm * 64 + mt * 16 + quad * 4;
                int bb = row >> 12, n = row & 4095;
                float bias = bhv[hch];
                bf16x4 pk = { f2bf(acc[mt][nt][0] + bias), f2bf(acc[mt][nt][1] + bias),
                              f2bf(acc[mt][nt][2] + bias), f2bf(acc[mt][nt][3] + bias) };
                *(bf16x4*)&hT[((size_t)(bb * 256 + hch)) * 4096 + n] = pk;
            }
        }
    }
}

// ---------------------------------------------------------------------------
// Kernel 2: attention v4.  32x32x16 MFMA, S^T trick, register-P, kv-split 4,
// 2 blocks/CU, m-split interleaved S/softmax/PV, exp2 path, perm-pack.
// ---------------------------------------------------------------------------
#define HST 40   // short stride for fs/hs rows (80B, 16B-aligned)

__global__ __launch_bounds__(256, 2) void attn_v4(
    const short* __restrict__ fK,    // keys    [B*N,64]
    const short* __restrict__ gQ,    // queries [B*N,64] (pre-scaled by log2e)
    const short* __restrict__ hT,    // values  [B,256,4096]
    short* __restrict__ oPartB,      // [4][B*N,256] bf16
    float* __restrict__ lPart)       // [4][B*N]
{
    const int bx = blockIdx.x;
    const int s  = bx & 3;
    const int qt = (bx >> 2) & 31;
    const int b  = bx >> 7;
    const int kb = s * 1024;
    const int t  = threadIdx.x;
    const int w  = t >> 6, lane = t & 63;
    const int l31 = lane & 31, h = lane >> 5;
    const int wq = w & 1, wv = w >> 1;
    const int q_wave = qt * 128 + wq * 64;

    __shared__ short fs[2][64 * HST];
    __shared__ short hs[2][256 * HST];

    // Q B-frags (B[k=d][n=q]: n=l31, k=16k+8h+j), held all kernel
    bf16x8 qf[2][4];
    #pragma unroll
    for (int n2 = 0; n2 < 2; n2++)
        #pragma unroll
        for (int k = 0; k < 4; k++)
            qf[n2][k] = *(const bf16x8*)&gQ[(size_t)(b * N_ + q_wave + n2 * 32 + l31) * 64 + k * 16 + h * 8];

    floatx16 oacc[2][4];
    #pragma unroll
    for (int n2 = 0; n2 < 2; n2++)
        #pragma unroll
        for (int vt = 0; vt < 4; vt++)
            #pragma unroll
            for (int j = 0; j < 16; j++) oacc[n2][vt][j] = 0.f;
    float lsum[2] = {0.f, 0.f};

    const int f_row = t >> 2, f_c = (t & 3) * 16;
    const int h_row = t >> 3, h_c = (t & 7) * 8;

    // prologue: stage tile 0
    {
        *(bf16x8*)&fs[0][f_row * HST + f_c] =
            *(const bf16x8*)&fK[(size_t)(b * N_ + kb + f_row) * 64 + f_c];
        *(bf16x8*)&fs[0][f_row * HST + f_c + 8] =
            *(const bf16x8*)&fK[(size_t)(b * N_ + kb + f_row) * 64 + f_c + 8];
        #pragma unroll
        for (int i = 0; i < 8; i++)
            *(bf16x8*)&hs[0][(h_row + i * 32) * HST + h_c] =
                *(const bf16x8*)&hT[((size_t)(b * 256 + h_row + i * 32)) * 4096 + kb + h_c];
    }
    __syncthreads();

    for (int it = 0; it < 16; ++it) {
        const int cur = it & 1;
        const bool more = (it < 15);
        const int kn = kb + (it + 1) * 64;

        // prefetch next tile to registers
        bf16x8 rf0, rf1, rh[8];
        if (more) {
            rf0 = *(const bf16x8*)&fK[(size_t)(b * N_ + kn + f_row) * 64 + f_c];
            rf1 = *(const bf16x8*)&fK[(size_t)(b * N_ + kn + f_row) * 64 + f_c + 8];
            #pragma unroll
            for (int i = 0; i < 8; i++)
                rh[i] = *(const bf16x8*)&hT[((size_t)(b * 256 + h_row + i * 32)) * 4096 + kn + h_c];
        }

        #pragma unroll
        for (int m = 0; m < 2; m++) {
            // ---- S^T = F @ Q^T for key half m (32 keys) ----
            bf16x8 ffr[4];
            #pragma unroll
            for (int k = 0; k < 4; k++)
                ffr[k] = *(const bf16x8*)&fs[cur][(m * 32 + l31) * HST + k * 16 + h * 8];

            floatx16 sacc[2];
            #pragma unroll
            for (int n2 = 0; n2 < 2; n2++)
                #pragma unroll
                for (int j = 0; j < 16; j++) sacc[n2][j] = 0.f;
            #pragma unroll
            for (int k = 0; k < 4; k++)
                #pragma unroll
                for (int n2 = 0; n2 < 2; n2++)
                    sacc[n2] = __builtin_amdgcn_mfma_f32_32x32x16_bf16(
                        ffr[k], qf[n2][k], sacc[n2], 0, 0, 0);

            // ---- exp2 + in-register transpose to PV A-frags ----
            bf16x8 pf[2][2];    // [n2][kp]
            #pragma unroll
            for (int n2 = 0; n2 < 2; n2++) {
                float p[16]; float ps_ = 0.f;
                #pragma unroll
                for (int j = 0; j < 16; j++) { p[j] = exp2f(sacc[n2][j]); ps_ += p[j]; }
                ps_ += __shfl_xor(ps_, 32);
                lsum[n2] += ps_;
                unsigned pk[8], xk[8];
                #pragma unroll
                for (int i = 0; i < 8; i++) pk[i] = pack2bf_fast(p[2 * i], p[2 * i + 1]);
                #pragma unroll
                for (int i = 0; i < 8; i++) xk[i] = __shfl_xor(pk[i], 32);
                #pragma unroll
                for (int kp = 0; kp < 2; kp++) {
                    U8 u;
                    u.u[0] = h ? xk[4 * kp + 2] : pk[4 * kp];
                    u.u[1] = h ? xk[4 * kp + 3] : pk[4 * kp + 1];
                    u.u[2] = h ? pk[4 * kp + 2] : xk[4 * kp];
                    u.u[3] = h ? pk[4 * kp + 3] : xk[4 * kp + 1];
                    pf[n2][kp] = u.v;
                }
            }

            // commit staging before the last PV chunk (frees prefetch regs;
            // writes go to buffer nxt, reads below use cur - no barrier needed)
            if (m == 1 && more) {
                const int nxt = cur ^ 1;
                *(bf16x8*)&fs[nxt][f_row * HST + f_c] = rf0;
                *(bf16x8*)&fs[nxt][f_row * HST + f_c + 8] = rf1;
                #pragma unroll
                for (int i = 0; i < 8; i++)
                    *(bf16x8*)&hs[nxt][(h_row + i * 32) * HST + h_c] = rh[i];
            }

            // ---- O += P @ V for this key half ----
            #pragma unroll
            for (int kp = 0; kp < 2; kp++) {
                const int kk = m * 2 + kp;
                #pragma unroll
                for (int vt = 0; vt < 4; vt++) {
                    bf16x8 vfr = *(const bf16x8*)&hs[cur][(wv * 128 + vt * 32 + l31) * HST + kk * 16 + h * 8];
                    #pragma unroll
                    for (int n2 = 0; n2 < 2; n2++)
                        oacc[n2][vt] = __builtin_amdgcn_mfma_f32_32x32x16_bf16(
                            pf[n2][kp], vfr, oacc[n2][vt], 0, 0, 0);
                }
            }
        }
        __syncthreads();
    }

    // ---- epilogue: store partial O (bf16) and partial l ----
    #pragma unroll
    for (int n2 = 0; n2 < 2; n2++) {
        #pragma unroll
        for (int vt = 0; vt < 4; vt++) {
            int vch = wv * 128 + vt * 32 + l31;
            #pragma unroll
            for (int r = 0; r < 16; r++) {
                int q = q_wave + n2 * 32 + (r & 3) + 8 * (r >> 2) + 4 * h;
                oPartB[(size_t)s * 4194304 + (size_t)(b * N_ + q) * 256 + vch] = f2bf(oacc[n2][vt][r]);
            }
        }
    }
    if (wv == 0 && lane < 32) {
        #pragma unroll
        for (int n2 = 0; n2 < 2; n2++)
            lPart[(size_t)s * 16384 + b * N_ + q_wave + n2 * 32 + lane] = lsum[n2];
    }
}

// ---------------------------------------------------------------------------
// Kernel 2b: combine kv-splits: obf = (sum_s O_s)/(sum_s l_s), bf16.
// ---------------------------------------------------------------------------
__global__ __launch_bounds__(256) void attn_combine(
    const short* __restrict__ oPartB, const float* __restrict__ lPart,
    short* __restrict__ obf)
{
    int idx = blockIdx.x * 256 + threadIdx.x;     // 512K threads, 8 ch each
    int row = idx >> 5;
    int c8  = (idx & 31) << 3;
    float acc[8] = {0.f,0.f,0.f,0.f,0.f,0.f,0.f,0.f};
    #pragma unroll
    for (int s = 0; s < 4; s++) {
        bf16x8 v = *(const bf16x8*)&oPartB[(size_t)s * 4194304 + (size_t)row * 256 + c8];
        #pragma unroll
        for (int j = 0; j < 8; j++) acc[j] += bf2f(v[j]);
    }
    float inv = 1.0f / (lPart[row] + lPart[16384 + row] +
                        lPart[32768 + row] + lPart[49152 + row]);
    bf16x8 o;
    #pragma unroll
    for (int j = 0; j < 8; j++) o[j] = f2bf(acc[j] * inv);
    *(bf16x8*)&obf[(size_t)row * 256 + c8] = o;
}

// ---------------------------------------------------------------------------
// Kernel 3: out = gamma*(o @ Wo + bo) + x  (LB(256,2))
// ---------------------------------------------------------------------------
__global__ __launch_bounds__(256, 2) void out_mfma(
    const short* __restrict__ obf, const short* __restrict__ WoT,
    const float* __restrict__ bo, const float* __restrict__ x,
    const float* __restrict__ gamma, float* __restrict__ out)
{
    const int n0 = blockIdx.x * 128;
    const int m0 = blockIdx.y * 128;
    const int t  = threadIdx.x;
    const int w  = t >> 6, lane = t & 63;
    const int l15 = lane & 15, quad = lane >> 4;
    const int wm = w & 1, wn = w >> 1;

    __shared__ short As[128 * 40];
    __shared__ short Bs[128 * 40];

    floatx4 acc[4][4];
    #pragma unroll
    for (int i = 0; i < 4; i++)
        #pragma unroll
        for (int j = 0; j < 4; j++) acc[i][j] = (floatx4){0.f,0.f,0.f,0.f};

    for (int k0 = 0; k0 < C2_; k0 += 32) {
        #pragma unroll
        for (int i = 0; i < 2; i++) {
            int c = t + i * 256;
            int row = c >> 2, ko = (c & 3) * 8;
            *(bf16x8*)&As[row * 40 + ko] =
                *(const bf16x8*)&obf[(size_t)(m0 + row) * 256 + k0 + ko];
        }
        #pragma unroll
        for (int i = 0; i < 2; i++) {
            int c = t + i * 256;
            int nr = c >> 2, ko = (c & 3) * 8;
            *(bf16x8*)&Bs[nr * 40 + ko] =
                *(const bf16x8*)&WoT[(size_t)(n0 + nr) * 256 + k0 + ko];
        }
        __syncthreads();

        bf16x8 af[4], bfr[4];
        #pragma unroll
        for (int mt = 0; mt < 4; mt++)
            af[mt] = *(const bf16x8*)&As[(wm * 64 + mt * 16 + l15) * 40 + quad * 8];
        #pragma unroll
        for (int nt = 0; nt < 4; nt++)
            bfr[nt] = *(const bf16x8*)&Bs[(wn * 64 + nt * 16 + l15) * 40 + quad * 8];
        #pragma unroll
        for (int mt = 0; mt < 4; mt++)
            #pragma unroll
            for (int nt = 0; nt < 4; nt++)
                acc[mt][nt] = __builtin_amdgcn_mfma_f32_16x16x32_bf16(af[mt], bfr[nt], acc[mt][nt], 0, 0, 0);
        __syncthreads();
    }

    const float gm = gamma[0];
    #pragma unroll
    for (int mt = 0; mt < 4; mt++) {
        #pragma unroll
        for (int nt = 0; nt < 4; nt++) {
            int col = n0 + wn * 64 + nt * 16 + l15;
            float bias = bo[col];
            #pragma unroll
            for (int rg = 0; rg < 4; rg++) {
                int row = m0 + wm * 64 + mt * 16 + quad * 4 + rg;
                out[(size_t)row * C_ + col] =
                    gm * (acc[mt][nt][rg] + bias) + x[(size_t)row * C_ + col];
            }
        }
    }
}

// ---------------------------------------------------------------------------
extern "C" void kernel_launch(void* const* d_in, const int* in_sizes, int n_in,
                              void* d_out, int out_size, void* d_ws, size_t ws_size,
                              hipStream_t stream) {
    (void)in_sizes; (void)n_in; (void)out_size; (void)ws_size;

    const float* x     = (const float*)d_in[0];
    const float* Wf    = (const float*)d_in[1];
    const float* bfv   = (const float*)d_in[2];
    const float* Wg    = (const float*)d_in[3];
    const float* bgv   = (const float*)d_in[4];
    const float* Wh    = (const float*)d_in[5];
    const float* bhv   = (const float*)d_in[6];
    const float* Wo    = (const float*)d_in[7];
    const float* bo    = (const float*)d_in[8];
    const float* gamma = (const float*)d_in[9];
    float* out = (float*)d_out;

    // ws layout (shorts): fbf 1M | gbf 1M | hT 4M | obf 4M | WcatT 192K |
    // WoT 128K | oPartB 16.8M | then lPart 64K f32    (~55 MB total)
    short* fbf    = (short*)d_ws;
    short* gbf    = fbf    + (size_t)B_ * N_ * C8_;
    short* hT     = gbf    + (size_t)B_ * N_ * C8_;
    short* obf    = hT     + (size_t)B_ * C2_ * N_;
    short* WcatT  = obf    + (size_t)B_ * N_ * C2_;
    short* WoT    = WcatT  + (size_t)384 * 512;
    short* oPartB = WoT    + (size_t)512 * 256;
    float* lPart  = (float*)(oPartB + (size_t)4 * 16384 * 256);

    convert_w<<<1280, 256, 0, stream>>>(Wf, Wg, Wh, Wo, WcatT, WoT);
    qkv_mfma<<<dim3(3, 128), 256, 0, stream>>>(x, WcatT, bfv, bgv, bhv, fbf, gbf, hT);
    attn_v4<<<512, 256, 0, stream>>>(fbf, gbf, hT, oPartB, lPart);
    attn_combine<<<2048, 256, 0, stream>>>(oPartB, lPart, obf);
    out_mfma<<<dim3(4, 128), 256, 0, stream>>>(obf, WoT, bo, x, gamma, out);
}